// Round 4
// baseline (219.121 us; speedup 1.0000x reference)
//
#include <hip/hip_runtime.h>

namespace {

typedef float f32x4 __attribute__((ext_vector_type(4)));

constexpr int S   = 32;    // neighbors
constexpr int F   = 128;   // features
constexpr int BR  = 32;    // rows per block (8 per wave)
constexpr int TPB = 256;   // 4 waves

// ---- Batcher odd-even mergesort network for 16 elements (63 CEs) ----
struct CEPair { int a, b; };

constexpr int batcher_count16() {
  int n = 16, cnt = 0;
  for (int p = 1; p < n; p <<= 1)
    for (int k = p; k >= 1; k >>= 1)
      for (int j = k % p; j + k < n; j += 2 * k)
        for (int i = 0; i < k && i + j + k < n; ++i)
          if ((i + j) / (2 * p) == (i + j + k) / (2 * p))
            ++cnt;
  return cnt;
}
constexpr int NCE = batcher_count16();   // 63

struct Net16 { CEPair ce[NCE]; };

constexpr Net16 make_net16() {
  Net16 net{};
  int n = 16, c = 0;
  for (int p = 1; p < n; p <<= 1)
    for (int k = p; k >= 1; k >>= 1)
      for (int j = k % p; j + k < n; j += 2 * k)
        for (int i = 0; i < k && i + j + k < n; ++i)
          if ((i + j) / (2 * p) == (i + j + k) / (2 * p))
            net.ce[c++] = CEPair{i + j, i + j + k};
  return net;
}
constexpr Net16 NET16 = make_net16();

__device__ __forceinline__ f32x4 min4(f32x4 a, f32x4 b) {
  f32x4 r;
  r.x = fminf(a.x, b.x); r.y = fminf(a.y, b.y);
  r.z = fminf(a.z, b.z); r.w = fminf(a.w, b.w);
  return r;
}
__device__ __forceinline__ f32x4 max4(f32x4 a, f32x4 b) {
  f32x4 r;
  r.x = fmaxf(a.x, b.x); r.y = fmaxf(a.y, b.y);
  r.z = fmaxf(a.z, b.z); r.w = fmaxf(a.w, b.w);
  return r;
}

template<int T>
__device__ __forceinline__ void sort16(f32x4 (&v)[16]) {
  if constexpr (T < NCE) {
    constexpr int a = NET16.ce[T].a;
    constexpr int b = NET16.ce[T].b;
    f32x4 x = v[a], y = v[b];
    v[a] = min4(x, y);
    v[b] = max4(x, y);
    sort16<T + 1>(v);
  }
}

// Barrier-free; each wave owns 8 rows end-to-end.
// Phase A: f32x4 lanes, row-PAIR per iteration:
//   lane = 32*h + c ; h = row parity, c = 16B feature chunk (4 features)
// -> half the load instructions of the f32x2 version and 32 KB in flight
//    per wave before the first waitcnt, at the same register cost.
__global__ __launch_bounds__(TPB, 3) void fused_median_gemm(
    const float* __restrict__ x,
    const float* __restrict__ neigh,
    const float* __restrict__ Ks,
    const float* __restrict__ Kn,
    const float* __restrict__ bias,
    float* __restrict__ out,
    int N)
{
    __shared__ __align__(16) float xs[4][8][F];   // 16 KB
    __shared__ __align__(16) float ms[4][8][F];   // 16 KB

    const int tid  = threadIdx.x;
    const int wv   = tid >> 6;                    // wave id 0..3
    const int lane = tid & 63;
    const int c    = lane & 31;                   // f32x4 chunk: features [c*4, c*4+4)
    const int h    = lane >> 5;                   // row parity within pair
    const int row0 = blockIdx.x * BR + wv * 8;

    // ---------- Phase A: rank-16-of-32 selection, 2 rows per iteration ----------
#pragma unroll 1
    for (int p = 0; p < 4; ++p) {
        const int rl = p * 2 + h;                 // local row 0..7
        int row = row0 + rl;
        if (row > N - 1) row = N - 1;             // tail clamp (duplicate work, same data)
        const f32x4* nb = (const f32x4*)(neigh + (size_t)row * (S * F));

        f32x4 A[16], B[16];
#pragma unroll
        for (int s = 0; s < 16; ++s) A[s] = nb[(size_t)s * 32 + c];
#pragma unroll
        for (int s = 0; s < 16; ++s) B[s] = nb[(size_t)(s + 16) * 32 + c];

        const f32x4 xv = ((const f32x4*)(x + (size_t)row * F))[c];

        sort16<0>(A);                             // ascending
        sort16<0>(B);                             // ascending

        // rank-16 (0-indexed) of merge(A,B): min_{i=1..16} max(A[i-1], B[16-i])
        // done in place: B dies after the max pass, min-tree collapses into A[0]
#pragma unroll
        for (int q = 0; q < 16; ++q) A[q] = max4(A[q], B[15 - q]);
#pragma unroll
        for (int st = 8; st >= 1; st >>= 1)
#pragma unroll
            for (int q = 0; q < st; ++q) A[q] = min4(A[q], A[q + st]);

        *(f32x4*)&ms[wv][rl][c * 4] = A[0];
        *(f32x4*)&xs[wv][rl][c * 4] = xv;
    }

    // wave-internal LDS visibility (waitcnt only, NOT a barrier)
    __threadfence_block();

    // ---------- Phase B: GEMM for this wave's 8 rows ----------
    // lane -> 4 output cols; lanes 0..31 self-half, 32..63 neigh-half
    const bool self_half = (lane < 32);
    const float* __restrict__ W = self_half ? Ks : Kn;
    const int wcol = (lane * 4) & 127;
    const float* lin = self_half ? &xs[wv][0][0] : &ms[wv][0][0];

    f32x4 acc[8];
#pragma unroll
    for (int r = 0; r < 8; ++r) acc[r] = f32x4{0.f, 0.f, 0.f, 0.f};

#pragma unroll 4
    for (int k4 = 0; k4 < 32; ++k4) {
        f32x4 wv4[4];
#pragma unroll
        for (int dk = 0; dk < 4; ++dk)
            wv4[dk] = *(const f32x4*)&W[(k4 * 4 + dk) * 128 + wcol];

        f32x4 xr[8];
#pragma unroll
        for (int r = 0; r < 8; ++r)
            xr[r] = *(const f32x4*)&lin[r * F + k4 * 4];   // wave-broadcast LDS read

#pragma unroll
        for (int r = 0; r < 8; ++r) {
#pragma unroll
            for (int dk = 0; dk < 4; ++dk) {
                const float s = xr[r][dk];
                acc[r].x = fmaf(s, wv4[dk].x, acc[r].x);
                acc[r].y = fmaf(s, wv4[dk].y, acc[r].y);
                acc[r].z = fmaf(s, wv4[dk].z, acc[r].z);
                acc[r].w = fmaf(s, wv4[dk].w, acc[r].w);
            }
        }
    }

    const f32x4 bv = *(const f32x4*)&bias[lane * 4];
#pragma unroll
    for (int r = 0; r < 8; ++r) {
        int row = row0 + r;
        if (row > N - 1) row = N - 1;   // duplicate store of identical values; benign
        f32x4 o;
        o.x = fmaxf(acc[r].x + bv.x, 0.f);
        o.y = fmaxf(acc[r].y + bv.y, 0.f);
        o.z = fmaxf(acc[r].z + bv.z, 0.f);
        o.w = fmaxf(acc[r].w + bv.w, 0.f);
        __builtin_nontemporal_store(o, (f32x4*)&out[(size_t)row * 256 + lane * 4]);
    }
}

} // namespace

extern "C" void kernel_launch(void* const* d_in, const int* in_sizes, int n_in,
                              void* d_out, int out_size, void* d_ws, size_t ws_size,
                              hipStream_t stream) {
    const float* x     = (const float*)d_in[0];
    const float* neigh = (const float*)d_in[1];
    const float* Ks    = (const float*)d_in[2];
    const float* Kn    = (const float*)d_in[3];
    const float* bias  = (const float*)d_in[4];
    float* out = (float*)d_out;

    const int N = in_sizes[0] / F;   // 50000
    const int grid = (N + BR - 1) / BR;
    hipLaunchKernelGGL(fused_median_gemm, dim3(grid), dim3(TPB), 0, stream,
                       x, neigh, Ks, Kn, bias, out, N);
}

// Round 5
// 183.648 us; speedup vs baseline: 1.1932x; 1.1932x over previous
//
#include <hip/hip_runtime.h>

namespace {

typedef float f32x2 __attribute__((ext_vector_type(2)));
typedef float f32x4 __attribute__((ext_vector_type(4)));

constexpr int S   = 32;    // neighbors
constexpr int F   = 128;   // features
constexpr int BR  = 32;    // rows per block (8 per wave)
constexpr int TPB = 256;   // 4 waves

// ---- Batcher odd-even mergesort network for 16 elements (63 CEs) ----
struct CEPair { int a, b; };

constexpr int batcher_count16() {
  int n = 16, cnt = 0;
  for (int p = 1; p < n; p <<= 1)
    for (int k = p; k >= 1; k >>= 1)
      for (int j = k % p; j + k < n; j += 2 * k)
        for (int i = 0; i < k && i + j + k < n; ++i)
          if ((i + j) / (2 * p) == (i + j + k) / (2 * p))
            ++cnt;
  return cnt;
}
constexpr int NCE = batcher_count16();   // 63

struct Net16 { CEPair ce[NCE]; };

constexpr Net16 make_net16() {
  Net16 net{};
  int n = 16, c = 0;
  for (int p = 1; p < n; p <<= 1)
    for (int k = p; k >= 1; k >>= 1)
      for (int j = k % p; j + k < n; j += 2 * k)
        for (int i = 0; i < k && i + j + k < n; ++i)
          if ((i + j) / (2 * p) == (i + j + k) / (2 * p))
            net.ce[c++] = CEPair{i + j, i + j + k};
  return net;
}
constexpr Net16 NET16 = make_net16();

__device__ __forceinline__ f32x2 min2(f32x2 a, f32x2 b) {
  f32x2 r; r.x = fminf(a.x, b.x); r.y = fminf(a.y, b.y); return r;
}
__device__ __forceinline__ f32x2 max2(f32x2 a, f32x2 b) {
  f32x2 r; r.x = fmaxf(a.x, b.x); r.y = fmaxf(a.y, b.y); return r;
}

template<int T>
__device__ __forceinline__ void sort16(f32x2 (&v)[16]) {
  if constexpr (T < NCE) {
    constexpr int a = NET16.ce[T].a;
    constexpr int b = NET16.ce[T].b;
    f32x2 x = v[a], y = v[b];
    v[a] = min2(x, y);
    v[b] = max2(x, y);
    sort16<T + 1>(v);
  }
}

// issue one row's 32 neighbor half-loads + x chunk (NO wait here; consumers
// wait via compiler-counted vmcnt, leaving other rows' loads in flight)
__device__ __forceinline__ void issue_row(const float* __restrict__ neigh,
                                          const float* __restrict__ x,
                                          int row, int lane,
                                          f32x2 (&A)[16], f32x2 (&B)[16],
                                          f32x2& xv)
{
    const f32x2* nb = (const f32x2*)(neigh + (size_t)row * (S * F)) + lane;
#pragma unroll
    for (int s = 0; s < 16; ++s)
        A[s] = __builtin_nontemporal_load(nb + (size_t)s * 64);
#pragma unroll
    for (int s = 0; s < 16; ++s)
        B[s] = __builtin_nontemporal_load(nb + (size_t)(s + 16) * 64);
    xv = *((const f32x2*)(x + (size_t)row * F) + lane);
}

// rank-16-of-32 (0-indexed) via two sorted 16-runs + in-place merge-select
__device__ __forceinline__ void select_store(f32x2 (&A)[16], f32x2 (&B)[16],
                                             f32x2 xv,
                                             float* __restrict__ msrow,
                                             float* __restrict__ xsrow,
                                             int lane)
{
    sort16<0>(A);
    sort16<0>(B);
#pragma unroll
    for (int q = 0; q < 16; ++q) A[q] = max2(A[q], B[15 - q]);
#pragma unroll
    for (int st = 8; st >= 1; st >>= 1)
#pragma unroll
        for (int q = 0; q < st; ++q) A[q] = min2(A[q], A[q + st]);
    ((f32x2*)msrow)[lane] = A[0];
    ((f32x2*)xsrow)[lane] = xv;
}

// Barrier-free, wave-owned rows, 2-deep ping-pong register prefetch:
// row r+1's 33 loads are ALWAYS outstanding while row r is being sorted,
// so the HBM stream never idles even if waves phase-lock chip-wide.
__global__ __launch_bounds__(TPB, 3) void fused_median_gemm(
    const float* __restrict__ x,
    const float* __restrict__ neigh,
    const float* __restrict__ Ks,
    const float* __restrict__ Kn,
    const float* __restrict__ bias,
    float* __restrict__ out,
    int N)
{
    __shared__ __align__(16) float xs[4][8][F];   // 16 KB
    __shared__ __align__(16) float ms[4][8][F];   // 16 KB

    const int tid  = threadIdx.x;
    const int wv   = tid >> 6;                    // wave id 0..3
    const int lane = tid & 63;                    // feature-pair index
    const int row0 = blockIdx.x * BR + wv * 8;

    const int rmax = N - 1;
    auto rw = [&](int rl) { int r = row0 + rl; return r > rmax ? rmax : r; };

    // ---------- Phase A: pipelined rank-16-of-32 over this wave's 8 rows ----------
    {
        f32x2 A0[16], B0[16], A1[16], B1[16];
        f32x2 x0, x1;

        issue_row(neigh, x, rw(0), lane, A0, B0, x0);
#pragma unroll
        for (int p = 0; p < 4; ++p) {
            issue_row(neigh, x, rw(2 * p + 1), lane, A1, B1, x1);   // prefetch odd row
            select_store(A0, B0, x0, &ms[wv][2 * p][0], &xs[wv][2 * p][0], lane);
            if (p < 3)
                issue_row(neigh, x, rw(2 * p + 2), lane, A0, B0, x0); // prefetch even row
            select_store(A1, B1, x1, &ms[wv][2 * p + 1][0], &xs[wv][2 * p + 1][0], lane);
        }
    }

    // drain this wave's LDS writes only (NOT vmcnt, NOT a barrier)
    asm volatile("s_waitcnt lgkmcnt(0)" ::: "memory");

    // ---------- Phase B: GEMM for this wave's 8 rows ----------
    // lane -> 4 output cols; lanes 0..31 self-half, 32..63 neigh-half
    const bool self_half = (lane < 32);
    const float* __restrict__ W = self_half ? Ks : Kn;
    const int wcol = (lane * 4) & 127;
    const float* lin = self_half ? &xs[wv][0][0] : &ms[wv][0][0];

    f32x4 acc[8];
#pragma unroll
    for (int r = 0; r < 8; ++r) acc[r] = f32x4{0.f, 0.f, 0.f, 0.f};

#pragma unroll 4
    for (int k4 = 0; k4 < 32; ++k4) {
        f32x4 wv4[4];
#pragma unroll
        for (int dk = 0; dk < 4; ++dk)
            wv4[dk] = *(const f32x4*)&W[(k4 * 4 + dk) * 128 + wcol];

        f32x4 xr[8];
#pragma unroll
        for (int r = 0; r < 8; ++r)
            xr[r] = *(const f32x4*)&lin[r * F + k4 * 4];   // wave-broadcast LDS read

#pragma unroll
        for (int r = 0; r < 8; ++r) {
#pragma unroll
            for (int dk = 0; dk < 4; ++dk) {
                const float s = xr[r][dk];
                acc[r].x = fmaf(s, wv4[dk].x, acc[r].x);
                acc[r].y = fmaf(s, wv4[dk].y, acc[r].y);
                acc[r].z = fmaf(s, wv4[dk].z, acc[r].z);
                acc[r].w = fmaf(s, wv4[dk].w, acc[r].w);
            }
        }
    }

    const f32x4 bv = *(const f32x4*)&bias[lane * 4];
#pragma unroll
    for (int r = 0; r < 8; ++r) {
        const int row = rw(r);   // tail: duplicate store of identical values; benign
        f32x4 o;
        o.x = fmaxf(acc[r].x + bv.x, 0.f);
        o.y = fmaxf(acc[r].y + bv.y, 0.f);
        o.z = fmaxf(acc[r].z + bv.z, 0.f);
        o.w = fmaxf(acc[r].w + bv.w, 0.f);
        __builtin_nontemporal_store(o, (f32x4*)&out[(size_t)row * 256 + lane * 4]);
    }
}

} // namespace

extern "C" void kernel_launch(void* const* d_in, const int* in_sizes, int n_in,
                              void* d_out, int out_size, void* d_ws, size_t ws_size,
                              hipStream_t stream) {
    const float* x     = (const float*)d_in[0];
    const float* neigh = (const float*)d_in[1];
    const float* Ks    = (const float*)d_in[2];
    const float* Kn    = (const float*)d_in[3];
    const float* bias  = (const float*)d_in[4];
    float* out = (float*)d_out;

    const int N = in_sizes[0] / F;   // 50000
    const int grid = (N + BR - 1) / BR;
    hipLaunchKernelGGL(fused_median_gemm, dim3(grid), dim3(TPB), 0, stream,
                       x, neigh, Ks, Kn, bias, out, N);
}